// Round 8
// baseline (322.264 us; speedup 1.0000x reference)
//
#include <hip/hip_runtime.h>

typedef __bf16 bf16;
typedef __bf16 bf16x8 __attribute__((ext_vector_type(8)));
typedef __bf16 bf16x4 __attribute__((ext_vector_type(4)));
typedef float f32x4 __attribute__((ext_vector_type(4)));
typedef float f32x16 __attribute__((ext_vector_type(16)));

// Pipeline (R6 structure restored): k_misc -> k_conv -> k_attn -> k_final.
// x: [256][4096] f32, conv_w: [1536][256] f32, out: [512][4096] f32
// qkvT per head (786432): [QT [4096][64] | KT [4096][64] | V [64][4096]]
// GroupNorm fusion: aK folds into Q fragments; bK's per-q corr cancels in O/L.
// V affine folds into k_final: out = a_v*(sum O)/(sum L) + b_v.
// k_attn: 64q/wave, S L-splits chosen at runtime from ws_size (8 preferred ->
// grid 1024 = 4 blocks/CU = 4 waves/SIMD; fallback 4 -> exact R6 config).

#define QF 0.18033688011112042f   // log2(e)/8
#define EXPF(x) __builtin_amdgcn_exp2f(x)
#define MFMA32(A, B, C) __builtin_amdgcn_mfma_f32_32x32x16_bf16(A, B, C, 0, 0, 0)

union U4 { bf16x4 v; unsigned u[2]; };
union U8 { bf16x8 v; unsigned u[4]; };

// ---------------- K_misc: LDS-tiled xpose+cast + cast_w + zero(cs) ----------------
__global__ void k_misc(const float* __restrict__ x, const float* __restrict__ w,
                       bf16* __restrict__ xT, bf16* __restrict__ wb, float* __restrict__ cs) {
    int b = blockIdx.x;
    if (b < 256) {
        __shared__ float ld[64][65];
        int cb = (b & 3) * 64;
        int pb = (b >> 2) * 64;
        int tp = (threadIdx.x & 15) * 4;   // px offset
        int tc = threadIdx.x >> 4;         // ch row 0..15
#pragma unroll
        for (int pass = 0; pass < 4; pass++) {
            int c = tc + pass * 16;
            float4 f = *(const float4*)(x + (cb + c) * 4096 + pb + tp);
            ld[tp][c] = f.x; ld[tp + 1][c] = f.y; ld[tp + 2][c] = f.z; ld[tp + 3][c] = f.w;
        }
        __syncthreads();
        int px = threadIdx.x >> 3;         // 0..31
        int co = (threadIdx.x & 7) * 8;    // 0..56
#pragma unroll
        for (int pass = 0; pass < 2; pass++) {
            int p2 = px + pass * 32;
            bf16x8 o;
#pragma unroll
            for (int j = 0; j < 8; j++) o[j] = (bf16)ld[p2][co + j];
            *(bf16x8*)(xT + (pb + p2) * 256 + cb + co) = o;
        }
    } else if (b < 640) {
        int idx = ((b - 256) * 256 + threadIdx.x) * 4;
        float4 f = *(const float4*)(w + idx);
        bf16x4 o;
        o[0] = (bf16)f.x; o[1] = (bf16)f.y; o[2] = (bf16)f.z; o[3] = (bf16)f.w;
        *(bf16x4*)(wb + idx) = o;
    } else {
#pragma unroll
        for (int i = 0; i < 12; i++) cs[i * 256 + threadIdx.x] = 0.f;
    }
}

// ---------------- K1: conv GEMM, LDS-staged fragments (round-2 proven version) ----------------
__global__ __launch_bounds__(256) void k_conv(const bf16* __restrict__ Wb,
                                              const bf16* __restrict__ xT,
                                              bf16* __restrict__ qkvT,
                                              float* __restrict__ cs) {
    __shared__ __attribute__((aligned(16))) bf16 xs[64 * 72];
    __shared__ __attribute__((aligned(16))) bf16 ws2[64 * 72];
    int wid = threadIdx.x >> 6, lane = threadIdx.x & 63;
    int quad = lane >> 4, l15 = lane & 15;
    int g  = blockIdx.x % 24;
    int pb = (blockIdx.x / 24) * 64;
    int h = g / 3, sec = g % 3;          // 0=key 1=query 2=value
    int ob = g * 64;

    int srow = threadIdx.x >> 2;          // 0..63
    int scol = (threadIdx.x & 3) * 16;    // 0/16/32/48

    f32x4 acc[4];
#pragma unroll
    for (int c = 0; c < 4; c++) acc[c] = (f32x4){0.f, 0.f, 0.f, 0.f};

    bf16x8 fx0 = *(const bf16x8*)(xT + (pb + srow) * 256 + scol);
    bf16x8 fx1 = *(const bf16x8*)(xT + (pb + srow) * 256 + scol + 8);
    bf16x8 fw0 = *(const bf16x8*)(Wb + (ob + srow) * 256 + scol);
    bf16x8 fw1 = *(const bf16x8*)(Wb + (ob + srow) * 256 + scol + 8);

    for (int c4 = 0; c4 < 4; c4++) {
        __syncthreads();
        *(bf16x8*)(xs  + srow * 72 + scol)     = fx0;
        *(bf16x8*)(xs  + srow * 72 + scol + 8) = fx1;
        *(bf16x8*)(ws2 + srow * 72 + scol)     = fw0;
        *(bf16x8*)(ws2 + srow * 72 + scol + 8) = fw1;
        __syncthreads();

        if (c4 < 3) {
            int co = (c4 + 1) * 64;
            fx0 = *(const bf16x8*)(xT + (pb + srow) * 256 + co + scol);
            fx1 = *(const bf16x8*)(xT + (pb + srow) * 256 + co + scol + 8);
            fw0 = *(const bf16x8*)(Wb + (ob + srow) * 256 + co + scol);
            fw1 = *(const bf16x8*)(Wb + (ob + srow) * 256 + co + scol + 8);
        }

#pragma unroll
        for (int k2 = 0; k2 < 2; k2++) {
            bf16x8 a = *(const bf16x8*)(ws2 + (wid * 16 + l15) * 72 + k2 * 32 + quad * 8);
#pragma unroll
            for (int c = 0; c < 4; c++) {
                bf16x8 b = *(const bf16x8*)(xs + (c * 16 + l15) * 72 + k2 * 32 + quad * 8);
                acc[c] = __builtin_amdgcn_mfma_f32_16x16x32_bf16(a, b, acc[c], 0, 0, 0);
            }
        }
    }

    int ch0 = wid * 16 + quad * 4;
#pragma unroll
    for (int r = 0; r < 4; r++) {
        float sp  = acc[0][r] + acc[1][r] + acc[2][r] + acc[3][r];
        float ssp = acc[0][r] * acc[0][r] + acc[1][r] * acc[1][r]
                  + acc[2][r] * acc[2][r] + acc[3][r] * acc[3][r];
#pragma unroll
        for (int m = 1; m < 16; m <<= 1) {
            sp  += __shfl_xor(sp,  m, 64);
            ssp += __shfl_xor(ssp, m, 64);
        }
        if (l15 == 0) {
            atomicAdd(cs + (ob + ch0 + r) * 2,     sp);
            atomicAdd(cs + (ob + ch0 + r) * 2 + 1, ssp);
        }
    }

    __syncthreads();
    bf16* tile = xs;
    if (sec == 2) {                       // V wants [ch][px]
#pragma unroll
        for (int c = 0; c < 4; c++)
#pragma unroll
            for (int r = 0; r < 4; r++)
                tile[(ch0 + r) * 72 + c * 16 + l15] = (bf16)acc[c][r];
    } else {                              // Q/K want [px][ch]
#pragma unroll
        for (int c = 0; c < 4; c++) {
            bf16x4 o;
#pragma unroll
            for (int r = 0; r < 4; r++) o[r] = (bf16)acc[c][r];
            *(bf16x4*)(&tile[(c * 16 + l15) * 72 + ch0]) = o;
        }
    }
    __syncthreads();
    bf16* base = qkvT + h * 786432;
    int t = threadIdx.x;
    if (sec == 2) {
        bf16* V = base + 524288;
#pragma unroll
        for (int it = 0; it < 2; it++) {
            int e = it * 256 + t; int ch = e >> 3; int pxo = (e & 7) * 8;
            *(bf16x8*)(V + ch * 4096 + pb + pxo) = *(const bf16x8*)(&tile[ch * 72 + pxo]);
        }
    } else {
        bf16* dst = base + (sec == 0 ? 262144 : 0);
#pragma unroll
        for (int it = 0; it < 2; it++) {
            int e = it * 256 + t; int px = e >> 3; int cho = (e & 7) * 8;
            *(bf16x8*)(dst + (pb + px) * 64 + cho) = *(const bf16x8*)(&tile[px * 72 + cho]);
        }
    }
}

// helper: one 32x32 C-block (S) -> exp2 -> two PV B-fragments (l-slices).
#define PF_BLOCK(S, LACC, PFA, PFB)                                             \
    {                                                                           \
        float p0 = EXPF(S[0]),  p1 = EXPF(S[1]),  p2 = EXPF(S[2]),  p3 = EXPF(S[3]);   \
        float p4 = EXPF(S[4]),  p5 = EXPF(S[5]),  p6 = EXPF(S[6]),  p7 = EXPF(S[7]);   \
        float p8 = EXPF(S[8]),  p9 = EXPF(S[9]),  p10 = EXPF(S[10]), p11 = EXPF(S[11]); \
        float p12 = EXPF(S[12]), p13 = EXPF(S[13]), p14 = EXPF(S[14]), p15 = EXPF(S[15]); \
        LACC += (((p0 + p1) + (p2 + p3)) + ((p4 + p5) + (p6 + p7)))             \
              + (((p8 + p9) + (p10 + p11)) + ((p12 + p13) + (p14 + p15)));      \
        U4 lo, hi;                                                              \
        lo.v[0] = (bf16)p0;  lo.v[1] = (bf16)p1;  lo.v[2] = (bf16)p2;  lo.v[3] = (bf16)p3;  \
        hi.v[0] = (bf16)p4;  hi.v[1] = (bf16)p5;  hi.v[2] = (bf16)p6;  hi.v[3] = (bf16)p7;  \
        unsigned a0 = lo.u[0], b0 = hi.u[0], a1 = lo.u[1], b1 = hi.u[1];        \
        asm("v_permlane32_swap_b32 %0, %1" : "+v"(a0), "+v"(b0));               \
        asm("v_permlane32_swap_b32 %0, %1" : "+v"(a1), "+v"(b1));               \
        U8 fA; fA.u[0] = a0; fA.u[1] = a1; fA.u[2] = b0; fA.u[3] = b1;          \
        PFA = fA.v;                                                             \
        U4 lo2, hi2;                                                            \
        lo2.v[0] = (bf16)p8;  lo2.v[1] = (bf16)p9;  lo2.v[2] = (bf16)p10; lo2.v[3] = (bf16)p11; \
        hi2.v[0] = (bf16)p12; hi2.v[1] = (bf16)p13; hi2.v[2] = (bf16)p14; hi2.v[3] = (bf16)p15; \
        unsigned a2 = lo2.u[0], b2 = hi2.u[0], a3 = lo2.u[1], b3 = hi2.u[1];    \
        asm("v_permlane32_swap_b32 %0, %1" : "+v"(a2), "+v"(b2));               \
        asm("v_permlane32_swap_b32 %0, %1" : "+v"(a3), "+v"(b3));               \
        U8 fB; fB.u[0] = a2; fB.u[1] = a3; fB.u[2] = b2; fB.u[3] = b3;          \
        PFB = fB.v;                                                             \
    }

#define STAGE(BK, BV)                                                           \
    *(bf16x8*)((BK) + r0 * 72 + koff)        = kf0;                             \
    *(bf16x8*)((BK) + (r0 + 32) * 72 + koff) = kf1;                             \
    *(bf16x8*)((BV) + r0 * 72 + koff)        = vf0;                             \
    *(bf16x8*)((BV) + (r0 + 32) * 72 + koff) = vf1;

#define PREFETCH(T)                                                             \
    {   int nb = (T) * 64;                                                      \
        kf0 = *(const bf16x8*)(KT + (nb + r0) * 64 + koff);                     \
        kf1 = *(const bf16x8*)(KT + (nb + r0 + 32) * 64 + koff);                \
        vf0 = *(const bf16x8*)(V + r0 * 4096 + nb + koff);                      \
        vf1 = *(const bf16x8*)(V + (r0 + 32) * 4096 + nb + koff); }

// QK for 64q: each K A-frag read feeds BOTH q-half MFMAs.
#define QK64(KSB)                                                               \
    {   const bf16* kra = (KSB) + l31 * 72 + half * 8;                          \
        const bf16* krb = (KSB) + (32 + l31) * 72 + half * 8;                   \
        __builtin_amdgcn_s_setprio(1);                                          \
        { bf16x8 fa = *(const bf16x8*)(kra +  0), fb = *(const bf16x8*)(krb +  0); \
          s00 = MFMA32(fa, bqA[0], s00); s01 = MFMA32(fa, bqB[0], s01);         \
          s10 = MFMA32(fb, bqA[0], s10); s11 = MFMA32(fb, bqB[0], s11); }       \
        { bf16x8 fa = *(const bf16x8*)(kra + 16), fb = *(const bf16x8*)(krb + 16); \
          s00 = MFMA32(fa, bqA[1], s00); s01 = MFMA32(fa, bqB[1], s01);         \
          s10 = MFMA32(fb, bqA[1], s10); s11 = MFMA32(fb, bqB[1], s11); }       \
        { bf16x8 fa = *(const bf16x8*)(kra + 32), fb = *(const bf16x8*)(krb + 32); \
          s00 = MFMA32(fa, bqA[2], s00); s01 = MFMA32(fa, bqB[2], s01);         \
          s10 = MFMA32(fb, bqA[2], s10); s11 = MFMA32(fb, bqB[2], s11); }       \
        { bf16x8 fa = *(const bf16x8*)(kra + 48), fb = *(const bf16x8*)(krb + 48); \
          s00 = MFMA32(fa, bqA[3], s00); s01 = MFMA32(fa, bqB[3], s01);         \
          s10 = MFMA32(fb, bqA[3], s10); s11 = MFMA32(fb, bqB[3], s11); }       \
        __builtin_amdgcn_s_setprio(0); }

// PV for 64q: each V A-frag read feeds BOTH q-half MFMAs.
#define PV64(VSB)                                                               \
    {   const bf16* vra = (VSB) + l31 * 72 + half * 8;                          \
        const bf16* vrb = (VSB) + (32 + l31) * 72 + half * 8;                   \
        __builtin_amdgcn_s_setprio(1);                                          \
        { bf16x8 fa = *(const bf16x8*)(vra +  0), fb = *(const bf16x8*)(vrb +  0); \
          oA0 = MFMA32(fa, pa0, oA0); oB0 = MFMA32(fa, pb0, oB0);               \
          oA1 = MFMA32(fb, pa0, oA1); oB1 = MFMA32(fb, pb0, oB1); }             \
        { bf16x8 fa = *(const bf16x8*)(vra + 16), fb = *(const bf16x8*)(vrb + 16); \
          oA0 = MFMA32(fa, pa1, oA0); oB0 = MFMA32(fa, pb1, oB0);               \
          oA1 = MFMA32(fb, pa1, oA1); oB1 = MFMA32(fb, pb1, oB1); }             \
        { bf16x8 fa = *(const bf16x8*)(vra + 32), fb = *(const bf16x8*)(vrb + 32); \
          oA0 = MFMA32(fa, pa2, oA0); oB0 = MFMA32(fa, pb2, oB0);               \
          oA1 = MFMA32(fb, pa2, oA1); oB1 = MFMA32(fb, pb2, oB1); }             \
        { bf16x8 fa = *(const bf16x8*)(vra + 48), fb = *(const bf16x8*)(vrb + 48); \
          oA0 = MFMA32(fa, pa3, oA0); oB0 = MFMA32(fa, pb3, oB0);               \
          oA1 = MFMA32(fb, pa3, oA1); oB1 = MFMA32(fb, pb3, oB1); }             \
        __builtin_amdgcn_s_setprio(0); }

// ---------------- K3: flash attention, 64q/wave, runtime L-splits ----------------
// grid 128*S = 8 heads x 16 q-blocks(256q) x S splits; ntps = 64/S tiles/split.
// S=8 -> 4 blocks/CU (4 waves/SIMD); LDS 4x36.9=147.5KB <=160, VGPR<=128.
__global__ __launch_bounds__(256, 4) void k_attn(const bf16* __restrict__ qkvT,
                                                 const float2* __restrict__ cs,
                                                 const float* __restrict__ gnw,
                                                 const float* __restrict__ gnb,
                                                 bf16* __restrict__ Opart,
                                                 float* __restrict__ Lsum,
                                                 int ntps) {
    int bid   = blockIdx.x;
    int h     = bid & 7;                  // XCD L2 affinity
    int qb    = (bid >> 3) & 15;
    int split = bid >> 7;                 // 0..S-1
    int wid = threadIdx.x >> 6, lane = threadIdx.x & 63;
    int l31 = lane & 31, half = lane >> 5;
    const bf16* QT = qkvT + h * 786432;
    const bf16* KT = QT + 262144;
    const bf16* V  = QT + 524288;
    int qw = qb * 256 + wid * 64;         // wave's 64 q

    __shared__ __attribute__((aligned(16))) bf16 Ks[2][64 * 72];
    __shared__ __attribute__((aligned(16))) bf16 Vs[2][64 * 72];

    int r0   = threadIdx.x >> 3;          // staging rows r0 and r0+32
    int koff = (threadIdx.x & 7) * 8;

    // ---- group stats (K: g=3h, Q: g=3h+1) from conv sums ----
    float2 vK = cs[(h * 3) * 64 + lane];
    float2 vQ = cs[(h * 3 + 1) * 64 + lane];
    float sK = vK.x, qK = vK.y, sQ = vQ.x, qQ = vQ.y;
#pragma unroll
    for (int m = 1; m < 64; m <<= 1) {
        sK += __shfl_xor(sK, m, 64); qK += __shfl_xor(qK, m, 64);
        sQ += __shfl_xor(sQ, m, 64); qQ += __shfl_xor(qQ, m, 64);
    }
    const float N = 262144.0f;
    float meanK = sK / N, invK = rsqrtf(qK / N - meanK * meanK + 1e-5f);
    float meanQ = sQ / N, invQ = rsqrtf(qQ / N - meanQ * meanQ + 1e-5f);

    // Q B-fragments for both q-halves: Qn*QF with K's scale aK folded in.
    bf16x8 bqA[4], bqB[4];
#pragma unroll
    for (int ks = 0; ks < 4; ks++) {
        bf16x8 rawA = *(const bf16x8*)(QT + (qw + l31) * 64 + ks * 16 + half * 8);
        bf16x8 rawB = *(const bf16x8*)(QT + (qw + 32 + l31) * 64 + ks * 16 + half * 8);
#pragma unroll
        for (int j = 0; j < 8; j++) {
            int c = ks * 16 + half * 8 + j;
            float gwq = gnw[h * 192 + 64 + c] * invQ;
            float bvq = (gnb[h * 192 + 64 + c] - meanQ * gwq) * QF;
            float avq = gwq * QF;
            float aKc = gnw[h * 192 + c] * invK;
            bqA[ks][j] = (bf16)(aKc * (avq * (float)rawA[j] + bvq));
            bqB[ks][j] = (bf16)(aKc * (avq * (float)rawB[j] + bvq));
        }
    }

    f32x16 oA0 = (f32x16)(0.0f), oA1 = (f32x16)(0.0f);   // qA: kd 0-31, 32-63
    f32x16 oB0 = (f32x16)(0.0f), oB1 = (f32x16)(0.0f);   // qB
    f32x16 s00, s01, s10, s11;
    bf16x8 pa0, pa1, pa2, pa3, pb0, pb1, pb2, pb3;
    float ls0 = 0.f, ls1 = 0.f;

    int t0 = split * ntps, t1 = t0 + ntps;

    bf16x8 kf0, kf1, vf0, vf1;
    PREFETCH(t0);

    for (int lt = t0; lt < t1; lt++) {
        bf16* ksb = Ks[lt & 1];
        bf16* vsb = Vs[lt & 1];
        STAGE(ksb, vsb);
        __syncthreads();                   // only barrier per tile
        if (lt + 1 < t1) PREFETCH(lt + 1);

        s00 = (f32x16)(0.0f); s01 = (f32x16)(0.0f);
        s10 = (f32x16)(0.0f); s11 = (f32x16)(0.0f);
        QK64(ksb);

        {
            float la0 = ls0, la1 = ls1;
            PF_BLOCK(s00, la0, pa0, pa1);  // qA, l 0-31
            PF_BLOCK(s10, la0, pa2, pa3);  // qA, l 32-63
            PF_BLOCK(s01, la1, pb0, pb1);  // qB, l 0-31
            PF_BLOCK(s11, la1, pb2, pb3);  // qB, l 32-63
            ls0 = la0; ls1 = la1;
        }

        PV64(vsb);
    }

    // denominator: halves hold complementary l-rows of col q
    ls0 += __shfl_xor(ls0, 32, 64);
    ls1 += __shfl_xor(ls1, 32, 64);
    if (half == 0) {
        Lsum[split * 32768 + h * 4096 + qw + l31]      = ls0;
        Lsum[split * 32768 + h * 4096 + qw + 32 + l31] = ls1;
    }

    // partial O (unnormalized, bf16): row = h*64+kd, col = q
    bf16* Ob = Opart + split * 2097152;
#pragma unroll
    for (int r = 0; r < 16; r++) {
        int kd = (r & 3) + 8 * (r >> 2) + 4 * half;
        Ob[(h * 64 + kd) * 4096 + qw + l31]           = (bf16)oA0[r];
        Ob[(h * 64 + 32 + kd) * 4096 + qw + l31]      = (bf16)oA1[r];
        Ob[(h * 64 + kd) * 4096 + qw + 32 + l31]      = (bf16)oB0[r];
        Ob[(h * 64 + 32 + kd) * 4096 + qw + 32 + l31] = (bf16)oB1[r];
    }
}

// ---------------- K4: combine S splits + V affine (stats inline) + normalize ----------------
__global__ void k_final(const bf16* __restrict__ Opart, const float* __restrict__ Lsum,
                        const float2* __restrict__ cs, const float* __restrict__ gnw,
                        const float* __restrict__ gnb, float* __restrict__ out, int S) {
    int gid = blockIdx.x * 256 + threadIdx.x;    // 262144
    int row = gid >> 9;
    int c8  = (gid & 511) << 3;
    int h   = row >> 6;

    int g = h * 3 + 2;
    int c = threadIdx.x & 63;
    float2 v = cs[g * 64 + c];
    float s = v.x, ss = v.y;
#pragma unroll
    for (int m = 1; m < 64; m <<= 1) { s += __shfl_xor(s, m, 64); ss += __shfl_xor(ss, m, 64); }
    const float N = 262144.0f;
    float mean = s / N;
    float inv  = rsqrtf(ss / N - mean * mean + 1e-5f);
    int gi = h * 192 + 128 + (row & 63);
    float gw = gnw[gi];
    float va = inv * gw;
    float vb = gnb[gi] - mean * inv * gw;

    float o[8] = {0, 0, 0, 0, 0, 0, 0, 0};
    float l[8] = {0, 0, 0, 0, 0, 0, 0, 0};
    for (int sp = 0; sp < S; sp++) {
        bf16x8 vv = *(const bf16x8*)(Opart + sp * 2097152 + row * 4096 + c8);
        const float* L = Lsum + sp * 32768 + h * 4096 + c8;
        float4 l0 = *(const float4*)L;
        float4 l1 = *(const float4*)(L + 4);
#pragma unroll
        for (int j = 0; j < 8; j++) o[j] += (float)vv[j];
        l[0] += l0.x; l[1] += l0.y; l[2] += l0.z; l[3] += l0.w;
        l[4] += l1.x; l[5] += l1.y; l[6] += l1.z; l[7] += l1.w;
    }
    float4 r0, r1;
    r0.x = va * o[0] / l[0] + vb; r0.y = va * o[1] / l[1] + vb;
    r0.z = va * o[2] / l[2] + vb; r0.w = va * o[3] / l[3] + vb;
    r1.x = va * o[4] / l[4] + vb; r1.y = va * o[5] / l[5] + vb;
    r1.z = va * o[6] / l[6] + vb; r1.w = va * o[7] / l[7] + vb;
    *(float4*)(out + row * 4096 + c8)     = r0;
    *(float4*)(out + row * 4096 + c8 + 4) = r1;
}

extern "C" void kernel_launch(void* const* d_in, const int* in_sizes, int n_in,
                              void* d_out, int out_size, void* d_ws, size_t ws_size,
                              hipStream_t stream) {
    const float* x      = (const float*)d_in[0];
    const float* conv_w = (const float*)d_in[1];
    const float* gn_w   = (const float*)d_in[2];
    const float* gn_b   = (const float*)d_in[3];
    float* out = (float*)d_out;
    char* ws = (char*)d_ws;

    // Layout: qkvT [0,12582912); Opart S x 4MB; Lsum S x 128KB; cs 12KB.
    // Wb/xT alias the Opart region (dead after k_conv).
    // S=8 needs ~47.2 MB; fall back to S=4 (R6 config, ~30 MB) if ws is small.
    int S = (ws_size >= (size_t)(12582912 + 8 * 4194304 + 8 * 131072 + 12288)) ? 8 : 4;

    bf16*   qkvT  = (bf16*) (ws);
    bf16*   Opart = (bf16*) (ws + 12582912);
    bf16*   Wb    = (bf16*) (ws + 12582912);
    bf16*   xT    = (bf16*) (ws + 13369344);
    float*  Lsum  = (float*)(ws + 12582912 + (size_t)S * 4194304);
    float*  cs    = Lsum + (size_t)S * 32768;

    hipLaunchKernelGGL(k_misc,  dim3(641),  dim3(256), 0, stream, x, conv_w, xT, Wb, cs);
    hipLaunchKernelGGL(k_conv,  dim3(1536), dim3(256), 0, stream, Wb, xT, qkvT, cs);
    hipLaunchKernelGGL(k_attn,  dim3(128 * S), dim3(256), 0, stream, qkvT, (const float2*)cs,
                       gn_w, gn_b, Opart, Lsum, 64 / S);
    hipLaunchKernelGGL(k_final, dim3(1024), dim3(256), 0, stream, Opart, Lsum, (const float2*)cs,
                       gn_w, gn_b, out, S);
}

// Round 9
// 130.092 us; speedup vs baseline: 2.4772x; 2.4772x over previous
//
#include <hip/hip_runtime.h>

typedef __bf16 bf16;
typedef __bf16 bf16x8 __attribute__((ext_vector_type(8)));
typedef __bf16 bf16x4 __attribute__((ext_vector_type(4)));
typedef float f32x4 __attribute__((ext_vector_type(4)));
typedef float f32x16 __attribute__((ext_vector_type(16)));

// Pipeline: k_misc -> k_conv -> k_attn -> k_final (R6 proven structure).
// x: [256][4096] f32, conv_w: [1536][256] f32, out: [512][4096] f32
// qkvT per head (786432): [QT [4096][64] | KT [4096][64] | V [64][4096]]
// GroupNorm fusion: aK folds into Q fragments; bK's per-q corr cancels in O/L.
// V affine folds into k_final: out = a_v*(sum O)/(sum L) + b_v.
// k_attn: 64q/wave (2 waves/SIMD — 244-reg footprint, unified VGPR+AGPR file),
// PV-deferred pipeline: per iter QK(t) + PV(t-1) form one 32-MFMA burst that
// co-schedules against the other wave's softmax; softmax(t) runs after.

#define QF 0.18033688011112042f   // log2(e)/8
#define EXPF(x) __builtin_amdgcn_exp2f(x)
#define MFMA32(A, B, C) __builtin_amdgcn_mfma_f32_32x32x16_bf16(A, B, C, 0, 0, 0)

union U4 { bf16x4 v; unsigned u[2]; };
union U8 { bf16x8 v; unsigned u[4]; };

// ---------------- K_misc: LDS-tiled xpose+cast + cast_w + zero(cs) ----------------
__global__ void k_misc(const float* __restrict__ x, const float* __restrict__ w,
                       bf16* __restrict__ xT, bf16* __restrict__ wb, float* __restrict__ cs) {
    int b = blockIdx.x;
    if (b < 256) {
        __shared__ float ld[64][65];
        int cb = (b & 3) * 64;
        int pb = (b >> 2) * 64;
        int tp = (threadIdx.x & 15) * 4;   // px offset
        int tc = threadIdx.x >> 4;         // ch row 0..15
#pragma unroll
        for (int pass = 0; pass < 4; pass++) {
            int c = tc + pass * 16;
            float4 f = *(const float4*)(x + (cb + c) * 4096 + pb + tp);
            ld[tp][c] = f.x; ld[tp + 1][c] = f.y; ld[tp + 2][c] = f.z; ld[tp + 3][c] = f.w;
        }
        __syncthreads();
        int px = threadIdx.x >> 3;         // 0..31
        int co = (threadIdx.x & 7) * 8;    // 0..56
#pragma unroll
        for (int pass = 0; pass < 2; pass++) {
            int p2 = px + pass * 32;
            bf16x8 o;
#pragma unroll
            for (int j = 0; j < 8; j++) o[j] = (bf16)ld[p2][co + j];
            *(bf16x8*)(xT + (pb + p2) * 256 + cb + co) = o;
        }
    } else if (b < 640) {
        int idx = ((b - 256) * 256 + threadIdx.x) * 4;
        float4 f = *(const float4*)(w + idx);
        bf16x4 o;
        o[0] = (bf16)f.x; o[1] = (bf16)f.y; o[2] = (bf16)f.z; o[3] = (bf16)f.w;
        *(bf16x4*)(wb + idx) = o;
    } else {
#pragma unroll
        for (int i = 0; i < 12; i++) cs[i * 256 + threadIdx.x] = 0.f;
    }
}

// ---------------- K1: conv GEMM, LDS-staged fragments (round-2 proven version) ----------------
__global__ __launch_bounds__(256) void k_conv(const bf16* __restrict__ Wb,
                                              const bf16* __restrict__ xT,
                                              bf16* __restrict__ qkvT,
                                              float* __restrict__ cs) {
    __shared__ __attribute__((aligned(16))) bf16 xs[64 * 72];
    __shared__ __attribute__((aligned(16))) bf16 ws2[64 * 72];
    int wid = threadIdx.x >> 6, lane = threadIdx.x & 63;
    int quad = lane >> 4, l15 = lane & 15;
    int g  = blockIdx.x % 24;
    int pb = (blockIdx.x / 24) * 64;
    int h = g / 3, sec = g % 3;          // 0=key 1=query 2=value
    int ob = g * 64;

    int srow = threadIdx.x >> 2;          // 0..63
    int scol = (threadIdx.x & 3) * 16;    // 0/16/32/48

    f32x4 acc[4];
#pragma unroll
    for (int c = 0; c < 4; c++) acc[c] = (f32x4){0.f, 0.f, 0.f, 0.f};

    bf16x8 fx0 = *(const bf16x8*)(xT + (pb + srow) * 256 + scol);
    bf16x8 fx1 = *(const bf16x8*)(xT + (pb + srow) * 256 + scol + 8);
    bf16x8 fw0 = *(const bf16x8*)(Wb + (ob + srow) * 256 + scol);
    bf16x8 fw1 = *(const bf16x8*)(Wb + (ob + srow) * 256 + scol + 8);

    for (int c4 = 0; c4 < 4; c4++) {
        __syncthreads();
        *(bf16x8*)(xs  + srow * 72 + scol)     = fx0;
        *(bf16x8*)(xs  + srow * 72 + scol + 8) = fx1;
        *(bf16x8*)(ws2 + srow * 72 + scol)     = fw0;
        *(bf16x8*)(ws2 + srow * 72 + scol + 8) = fw1;
        __syncthreads();

        if (c4 < 3) {
            int co = (c4 + 1) * 64;
            fx0 = *(const bf16x8*)(xT + (pb + srow) * 256 + co + scol);
            fx1 = *(const bf16x8*)(xT + (pb + srow) * 256 + co + scol + 8);
            fw0 = *(const bf16x8*)(Wb + (ob + srow) * 256 + co + scol);
            fw1 = *(const bf16x8*)(Wb + (ob + srow) * 256 + co + scol + 8);
        }

#pragma unroll
        for (int k2 = 0; k2 < 2; k2++) {
            bf16x8 a = *(const bf16x8*)(ws2 + (wid * 16 + l15) * 72 + k2 * 32 + quad * 8);
#pragma unroll
            for (int c = 0; c < 4; c++) {
                bf16x8 b = *(const bf16x8*)(xs + (c * 16 + l15) * 72 + k2 * 32 + quad * 8);
                acc[c] = __builtin_amdgcn_mfma_f32_16x16x32_bf16(a, b, acc[c], 0, 0, 0);
            }
        }
    }

    int ch0 = wid * 16 + quad * 4;
#pragma unroll
    for (int r = 0; r < 4; r++) {
        float sp  = acc[0][r] + acc[1][r] + acc[2][r] + acc[3][r];
        float ssp = acc[0][r] * acc[0][r] + acc[1][r] * acc[1][r]
                  + acc[2][r] * acc[2][r] + acc[3][r] * acc[3][r];
#pragma unroll
        for (int m = 1; m < 16; m <<= 1) {
            sp  += __shfl_xor(sp,  m, 64);
            ssp += __shfl_xor(ssp, m, 64);
        }
        if (l15 == 0) {
            atomicAdd(cs + (ob + ch0 + r) * 2,     sp);
            atomicAdd(cs + (ob + ch0 + r) * 2 + 1, ssp);
        }
    }

    __syncthreads();
    bf16* tile = xs;
    if (sec == 2) {                       // V wants [ch][px]
#pragma unroll
        for (int c = 0; c < 4; c++)
#pragma unroll
            for (int r = 0; r < 4; r++)
                tile[(ch0 + r) * 72 + c * 16 + l15] = (bf16)acc[c][r];
    } else {                              // Q/K want [px][ch]
#pragma unroll
        for (int c = 0; c < 4; c++) {
            bf16x4 o;
#pragma unroll
            for (int r = 0; r < 4; r++) o[r] = (bf16)acc[c][r];
            *(bf16x4*)(&tile[(c * 16 + l15) * 72 + ch0]) = o;
        }
    }
    __syncthreads();
    bf16* base = qkvT + h * 786432;
    int t = threadIdx.x;
    if (sec == 2) {
        bf16* V = base + 524288;
#pragma unroll
        for (int it = 0; it < 2; it++) {
            int e = it * 256 + t; int ch = e >> 3; int pxo = (e & 7) * 8;
            *(bf16x8*)(V + ch * 4096 + pb + pxo) = *(const bf16x8*)(&tile[ch * 72 + pxo]);
        }
    } else {
        bf16* dst = base + (sec == 0 ? 262144 : 0);
#pragma unroll
        for (int it = 0; it < 2; it++) {
            int e = it * 256 + t; int px = e >> 3; int cho = (e & 7) * 8;
            *(bf16x8*)(dst + (pb + px) * 64 + cho) = *(const bf16x8*)(&tile[px * 72 + cho]);
        }
    }
}

// helper: one 32x32 C-block (S) -> exp2 -> two PV B-fragments (l-slices).
#define PF_BLOCK(S, LACC, PFA, PFB)                                             \
    {                                                                           \
        float p0 = EXPF(S[0]),  p1 = EXPF(S[1]),  p2 = EXPF(S[2]),  p3 = EXPF(S[3]);   \
        float p4 = EXPF(S[4]),  p5 = EXPF(S[5]),  p6 = EXPF(S[6]),  p7 = EXPF(S[7]);   \
        float p8 = EXPF(S[8]),  p9 = EXPF(S[9]),  p10 = EXPF(S[10]), p11 = EXPF(S[11]); \
        float p12 = EXPF(S[12]), p13 = EXPF(S[13]), p14 = EXPF(S[14]), p15 = EXPF(S[15]); \
        LACC += (((p0 + p1) + (p2 + p3)) + ((p4 + p5) + (p6 + p7)))             \
              + (((p8 + p9) + (p10 + p11)) + ((p12 + p13) + (p14 + p15)));      \
        U4 lo, hi;                                                              \
        lo.v[0] = (bf16)p0;  lo.v[1] = (bf16)p1;  lo.v[2] = (bf16)p2;  lo.v[3] = (bf16)p3;  \
        hi.v[0] = (bf16)p4;  hi.v[1] = (bf16)p5;  hi.v[2] = (bf16)p6;  hi.v[3] = (bf16)p7;  \
        unsigned a0 = lo.u[0], b0 = hi.u[0], a1 = lo.u[1], b1 = hi.u[1];        \
        asm("v_permlane32_swap_b32 %0, %1" : "+v"(a0), "+v"(b0));               \
        asm("v_permlane32_swap_b32 %0, %1" : "+v"(a1), "+v"(b1));               \
        U8 fA; fA.u[0] = a0; fA.u[1] = a1; fA.u[2] = b0; fA.u[3] = b1;          \
        PFA = fA.v;                                                             \
        U4 lo2, hi2;                                                            \
        lo2.v[0] = (bf16)p8;  lo2.v[1] = (bf16)p9;  lo2.v[2] = (bf16)p10; lo2.v[3] = (bf16)p11; \
        hi2.v[0] = (bf16)p12; hi2.v[1] = (bf16)p13; hi2.v[2] = (bf16)p14; hi2.v[3] = (bf16)p15; \
        unsigned a2 = lo2.u[0], b2 = hi2.u[0], a3 = lo2.u[1], b3 = hi2.u[1];    \
        asm("v_permlane32_swap_b32 %0, %1" : "+v"(a2), "+v"(b2));               \
        asm("v_permlane32_swap_b32 %0, %1" : "+v"(a3), "+v"(b3));               \
        U8 fB; fB.u[0] = a2; fB.u[1] = a3; fB.u[2] = b2; fB.u[3] = b3;          \
        PFB = fB.v;                                                             \
    }

#define STAGE(BK, BV)                                                           \
    *(bf16x8*)((BK) + r0 * 72 + koff)        = kf0;                             \
    *(bf16x8*)((BK) + (r0 + 32) * 72 + koff) = kf1;                             \
    *(bf16x8*)((BV) + r0 * 72 + koff)        = vf0;                             \
    *(bf16x8*)((BV) + (r0 + 32) * 72 + koff) = vf1;

#define PREFETCH(T)                                                             \
    {   int nb = (T) * 64;                                                      \
        kf0 = *(const bf16x8*)(KT + (nb + r0) * 64 + koff);                     \
        kf1 = *(const bf16x8*)(KT + (nb + r0 + 32) * 64 + koff);                \
        vf0 = *(const bf16x8*)(V + r0 * 4096 + nb + koff);                      \
        vf1 = *(const bf16x8*)(V + (r0 + 32) * 4096 + nb + koff); }

// QK for 64q: each K A-frag read feeds BOTH q-half MFMAs.
#define QK64(KSB)                                                               \
    {   const bf16* kra = (KSB) + l31 * 72 + half * 8;                          \
        const bf16* krb = (KSB) + (32 + l31) * 72 + half * 8;                   \
        s00 = (f32x16)(0.0f); s01 = (f32x16)(0.0f);                             \
        s10 = (f32x16)(0.0f); s11 = (f32x16)(0.0f);                             \
        __builtin_amdgcn_s_setprio(1);                                          \
        { bf16x8 fa = *(const bf16x8*)(kra +  0), fb = *(const bf16x8*)(krb +  0); \
          s00 = MFMA32(fa, bqA[0], s00); s01 = MFMA32(fa, bqB[0], s01);         \
          s10 = MFMA32(fb, bqA[0], s10); s11 = MFMA32(fb, bqB[0], s11); }       \
        { bf16x8 fa = *(const bf16x8*)(kra + 16), fb = *(const bf16x8*)(krb + 16); \
          s00 = MFMA32(fa, bqA[1], s00); s01 = MFMA32(fa, bqB[1], s01);         \
          s10 = MFMA32(fb, bqA[1], s10); s11 = MFMA32(fb, bqB[1], s11); }       \
        { bf16x8 fa = *(const bf16x8*)(kra + 32), fb = *(const bf16x8*)(krb + 32); \
          s00 = MFMA32(fa, bqA[2], s00); s01 = MFMA32(fa, bqB[2], s01);         \
          s10 = MFMA32(fb, bqA[2], s10); s11 = MFMA32(fb, bqB[2], s11); }       \
        { bf16x8 fa = *(const bf16x8*)(kra + 48), fb = *(const bf16x8*)(krb + 48); \
          s00 = MFMA32(fa, bqA[3], s00); s01 = MFMA32(fa, bqB[3], s01);         \
          s10 = MFMA32(fb, bqA[3], s10); s11 = MFMA32(fb, bqB[3], s11); }       \
        __builtin_amdgcn_s_setprio(0); }

// PV for 64q: each V A-frag read feeds BOTH q-half MFMAs.
#define PV64(VSB)                                                               \
    {   const bf16* vra = (VSB) + l31 * 72 + half * 8;                          \
        const bf16* vrb = (VSB) + (32 + l31) * 72 + half * 8;                   \
        __builtin_amdgcn_s_setprio(1);                                          \
        { bf16x8 fa = *(const bf16x8*)(vra +  0), fb = *(const bf16x8*)(vrb +  0); \
          oA0 = MFMA32(fa, pa0, oA0); oB0 = MFMA32(fa, pb0, oB0);               \
          oA1 = MFMA32(fb, pa0, oA1); oB1 = MFMA32(fb, pb0, oB1); }             \
        { bf16x8 fa = *(const bf16x8*)(vra + 16), fb = *(const bf16x8*)(vrb + 16); \
          oA0 = MFMA32(fa, pa1, oA0); oB0 = MFMA32(fa, pb1, oB0);               \
          oA1 = MFMA32(fb, pa1, oA1); oB1 = MFMA32(fb, pb1, oB1); }             \
        { bf16x8 fa = *(const bf16x8*)(vra + 32), fb = *(const bf16x8*)(vrb + 32); \
          oA0 = MFMA32(fa, pa2, oA0); oB0 = MFMA32(fa, pb2, oB0);               \
          oA1 = MFMA32(fb, pa2, oA1); oB1 = MFMA32(fb, pb2, oB1); }             \
        { bf16x8 fa = *(const bf16x8*)(vra + 48), fb = *(const bf16x8*)(vrb + 48); \
          oA0 = MFMA32(fa, pa3, oA0); oB0 = MFMA32(fa, pb3, oB0);               \
          oA1 = MFMA32(fb, pa3, oA1); oB1 = MFMA32(fb, pb3, oB1); }             \
        __builtin_amdgcn_s_setprio(0); }

#define SOFTMAX_ALL()                                                           \
    {   float la0 = ls0, la1 = ls1;                                             \
        PF_BLOCK(s00, la0, pa0, pa1);                                           \
        PF_BLOCK(s10, la0, pa2, pa3);                                           \
        PF_BLOCK(s01, la1, pb0, pb1);                                           \
        PF_BLOCK(s11, la1, pb2, pb3);                                           \
        ls0 = la0; ls1 = la1; }

// ---------------- K3: flash attention, 64q/wave, PV-deferred ----------------
// grid 512 = 8 heads x 16 q-blocks(256q) x 4 L-splits; wave owns 64 q.
// Per iter: B1; STAGE(t); B2; prefetch(t+1); QK(t); PV(t-1); softmax(t).
// B1 separates PV(t-2)'s reads of buf t&1 from STAGE(t)'s writes (race-free).
__global__ __launch_bounds__(256, 2) void k_attn(const bf16* __restrict__ qkvT,
                                                 const float2* __restrict__ cs,
                                                 const float* __restrict__ gnw,
                                                 const float* __restrict__ gnb,
                                                 bf16* __restrict__ Opart,
                                                 float* __restrict__ Lsum) {
    int bid   = blockIdx.x;
    int h     = bid & 7;                  // XCD L2 affinity
    int qb    = (bid >> 3) & 15;
    int split = bid >> 7;                 // 0..3
    int wid = threadIdx.x >> 6, lane = threadIdx.x & 63;
    int l31 = lane & 31, half = lane >> 5;
    const bf16* QT = qkvT + h * 786432;
    const bf16* KT = QT + 262144;
    const bf16* V  = QT + 524288;
    int qw = qb * 256 + wid * 64;         // wave's 64 q

    __shared__ __attribute__((aligned(16))) bf16 Ks[2][64 * 72];
    __shared__ __attribute__((aligned(16))) bf16 Vs[2][64 * 72];

    int r0   = threadIdx.x >> 3;          // staging rows r0 and r0+32
    int koff = (threadIdx.x & 7) * 8;

    // ---- group stats (K: g=3h, Q: g=3h+1) from conv sums ----
    float2 vK = cs[(h * 3) * 64 + lane];
    float2 vQ = cs[(h * 3 + 1) * 64 + lane];
    float sK = vK.x, qK = vK.y, sQ = vQ.x, qQ = vQ.y;
#pragma unroll
    for (int m = 1; m < 64; m <<= 1) {
        sK += __shfl_xor(sK, m, 64); qK += __shfl_xor(qK, m, 64);
        sQ += __shfl_xor(sQ, m, 64); qQ += __shfl_xor(qQ, m, 64);
    }
    const float N = 262144.0f;
    float meanK = sK / N, invK = rsqrtf(qK / N - meanK * meanK + 1e-5f);
    float meanQ = sQ / N, invQ = rsqrtf(qQ / N - meanQ * meanQ + 1e-5f);

    // Q B-fragments for both q-halves: Qn*QF with K's scale aK folded in.
    bf16x8 bqA[4], bqB[4];
#pragma unroll
    for (int ks = 0; ks < 4; ks++) {
        bf16x8 rawA = *(const bf16x8*)(QT + (qw + l31) * 64 + ks * 16 + half * 8);
        bf16x8 rawB = *(const bf16x8*)(QT + (qw + 32 + l31) * 64 + ks * 16 + half * 8);
#pragma unroll
        for (int j = 0; j < 8; j++) {
            int c = ks * 16 + half * 8 + j;
            float gwq = gnw[h * 192 + 64 + c] * invQ;
            float bvq = (gnb[h * 192 + 64 + c] - meanQ * gwq) * QF;
            float avq = gwq * QF;
            float aKc = gnw[h * 192 + c] * invK;
            bqA[ks][j] = (bf16)(aKc * (avq * (float)rawA[j] + bvq));
            bqB[ks][j] = (bf16)(aKc * (avq * (float)rawB[j] + bvq));
        }
    }

    f32x16 oA0 = (f32x16)(0.0f), oA1 = (f32x16)(0.0f);   // qA: kd 0-31, 32-63
    f32x16 oB0 = (f32x16)(0.0f), oB1 = (f32x16)(0.0f);   // qB
    f32x16 s00, s01, s10, s11;
    bf16x8 pa0, pa1, pa2, pa3, pb0, pb1, pb2, pb3;
    float ls0 = 0.f, ls1 = 0.f;

    int t0 = split * 16, t1 = t0 + 16;

    bf16x8 kf0, kf1, vf0, vf1;
    PREFETCH(t0);

    // ---- peel tile t0: stage, QK, softmax (no PV yet) ----
    STAGE(Ks[t0 & 1], Vs[t0 & 1]);
    __syncthreads();                      // B2: tile t0 visible
    PREFETCH(t0 + 1);
    QK64(Ks[t0 & 1]);
    SOFTMAX_ALL();

    for (int lt = t0 + 1; lt < t1; lt++) {
        __syncthreads();                  // B1: PV(lt-2) reads of buf lt&1 done
        STAGE(Ks[lt & 1], Vs[lt & 1]);
        __syncthreads();                  // B2: tile lt visible
        if (lt + 1 < t1) PREFETCH(lt + 1);
        QK64(Ks[lt & 1]);                 // 32-MFMA burst with...
        PV64(Vs[(lt - 1) & 1]);           // ...deferred PV (indep of softmax(lt))
        SOFTMAX_ALL();
    }
    PV64(Vs[(t1 - 1) & 1]);               // drain

    // denominator: halves hold complementary l-rows of col q
    ls0 += __shfl_xor(ls0, 32, 64);
    ls1 += __shfl_xor(ls1, 32, 64);
    if (half == 0) {
        Lsum[split * 32768 + h * 4096 + qw + l31]      = ls0;
        Lsum[split * 32768 + h * 4096 + qw + 32 + l31] = ls1;
    }

    // partial O (unnormalized, bf16): row = h*64+kd, col = q
    bf16* Ob = Opart + split * 2097152;
#pragma unroll
    for (int r = 0; r < 16; r++) {
        int kd = (r & 3) + 8 * (r >> 2) + 4 * half;
        Ob[(h * 64 + kd) * 4096 + qw + l31]           = (bf16)oA0[r];
        Ob[(h * 64 + 32 + kd) * 4096 + qw + l31]      = (bf16)oA1[r];
        Ob[(h * 64 + kd) * 4096 + qw + 32 + l31]      = (bf16)oB0[r];
        Ob[(h * 64 + 32 + kd) * 4096 + qw + 32 + l31] = (bf16)oB1[r];
    }
}

// ---------------- K4: combine 4 splits + V affine (stats inline) + normalize ----------------
__global__ void k_final(const bf16* __restrict__ Opart, const float* __restrict__ Lsum,
                        const float2* __restrict__ cs, const float* __restrict__ gnw,
                        const float* __restrict__ gnb, float* __restrict__ out) {
    int gid = blockIdx.x * 256 + threadIdx.x;    // 262144
    int row = gid >> 9;
    int c8  = (gid & 511) << 3;
    int h   = row >> 6;

    int g = h * 3 + 2;
    int c = threadIdx.x & 63;
    float2 v = cs[g * 64 + c];
    float s = v.x, ss = v.y;
#pragma unroll
    for (int m = 1; m < 64; m <<= 1) { s += __shfl_xor(s, m, 64); ss += __shfl_xor(ss, m, 64); }
    const float N = 262144.0f;
    float mean = s / N;
    float inv  = rsqrtf(ss / N - mean * mean + 1e-5f);
    int gi = h * 192 + 128 + (row & 63);
    float gw = gnw[gi];
    float va = inv * gw;
    float vb = gnb[gi] - mean * inv * gw;

    float o[8] = {0, 0, 0, 0, 0, 0, 0, 0};
    float l[8] = {0, 0, 0, 0, 0, 0, 0, 0};
#pragma unroll
    for (int sp = 0; sp < 4; sp++) {
        bf16x8 vv = *(const bf16x8*)(Opart + sp * 2097152 + row * 4096 + c8);
        const float* L = Lsum + sp * 32768 + h * 4096 + c8;
        float4 l0 = *(const float4*)L;
        float4 l1 = *(const float4*)(L + 4);
#pragma unroll
        for (int j = 0; j < 8; j++) o[j] += (float)vv[j];
        l[0] += l0.x; l[1] += l0.y; l[2] += l0.z; l[3] += l0.w;
        l[4] += l1.x; l[5] += l1.y; l[6] += l1.z; l[7] += l1.w;
    }
    float4 r0, r1;
    r0.x = va * o[0] / l[0] + vb; r0.y = va * o[1] / l[1] + vb;
    r0.z = va * o[2] / l[2] + vb; r0.w = va * o[3] / l[3] + vb;
    r1.x = va * o[4] / l[4] + vb; r1.y = va * o[5] / l[5] + vb;
    r1.z = va * o[6] / l[6] + vb; r1.w = va * o[7] / l[7] + vb;
    *(float4*)(out + row * 4096 + c8)     = r0;
    *(float4*)(out + row * 4096 + c8 + 4) = r1;
}

extern "C" void kernel_launch(void* const* d_in, const int* in_sizes, int n_in,
                              void* d_out, int out_size, void* d_ws, size_t ws_size,
                              hipStream_t stream) {
    const float* x      = (const float*)d_in[0];
    const float* conv_w = (const float*)d_in[1];
    const float* gn_w   = (const float*)d_in[2];
    const float* gn_b   = (const float*)d_in[3];
    float* out = (float*)d_out;
    char* ws = (char*)d_ws;

    // qkvT [0,12582912); Opart 4x4MB [12582912,29360128); Wb/xT alias Opart
    // (dead after k_conv; Opart first written by k_attn).
    bf16*   qkvT  = (bf16*) (ws);
    bf16*   Opart = (bf16*) (ws + 12582912);
    bf16*   Wb    = (bf16*) (ws + 12582912);
    bf16*   xT    = (bf16*) (ws + 13369344);
    float*  Lsum  = (float*)(ws + 29360128);        // 4*131072 B
    float*  cs    = (float*)(ws + 29884416);        // 12288 B

    hipLaunchKernelGGL(k_misc,  dim3(641),  dim3(256), 0, stream, x, conv_w, xT, Wb, cs);
    hipLaunchKernelGGL(k_conv,  dim3(1536), dim3(256), 0, stream, Wb, xT, qkvT, cs);
    hipLaunchKernelGGL(k_attn,  dim3(512),  dim3(256), 0, stream, qkvT, (const float2*)cs,
                       gn_w, gn_b, Opart, Lsum);
    hipLaunchKernelGGL(k_final, dim3(1024), dim3(256), 0, stream, Opart, Lsum, (const float2*)cs, gn_w, gn_b, out);
}